// Round 1
// baseline (999.693 us; speedup 1.0000x reference)
//
#include <hip/hip_runtime.h>
#include <hip/hip_bf16.h>

#define N_NODES   100000
#define N_EDGES   1600000
#define N_GRAPHS  1024
#define EMB       32
#define HID       64
#define N_CLASSES 10

// ---------------- degree count ----------------
__global__ __launch_bounds__(256) void deg_kernel(const int* __restrict__ dst,
                                                  int* __restrict__ degi) {
    int e = blockIdx.x * 256 + threadIdx.x;
    if (e < N_EDGES) atomicAdd(&degi[dst[e]], 1);
}

__global__ __launch_bounds__(256) void dis_kernel(const int* __restrict__ degi,
                                                  float* __restrict__ dis) {
    int v = blockIdx.x * 256 + threadIdx.x;
    if (v < N_NODES) dis[v] = rsqrtf(1.0f + (float)degi[v]);
}

// ---------------- embed + matmul1 (x = emb(shape)+emb(color); h1 = x @ W1) ----------------
// block = 256 threads = 4 nodes x 64 output channels
__global__ __launch_bounds__(256) void embed_mm1_kernel(
    const int* __restrict__ sid, const int* __restrict__ cid,
    const float* __restrict__ st, const float* __restrict__ ct,
    const float* __restrict__ W1, float* __restrict__ h1) {
    __shared__ float W1s[EMB * HID];   // 8 KB
    __shared__ float xs[4][EMB];
    int t = threadIdx.x;
    for (int i = t; i < EMB * HID; i += 256) W1s[i] = W1[i];
    int nl = t >> 6, j = t & 63;
    int v = blockIdx.x * 4 + nl;   // grid sized so v < N_NODES always (100000 = 4*25000)
    if (j < EMB) {
        int s = sid[v], c = cid[v];
        float val = 0.0f;
        if (s != 0) val += st[s * EMB + j];
        if (c != 0) val += ct[c * EMB + j];
        xs[nl][j] = val;
    }
    __syncthreads();
    float acc = 0.0f;
#pragma unroll
    for (int k = 0; k < EMB; ++k) acc = fmaf(xs[nl][k], W1s[k * HID + j], acc);
    h1[v * HID + j] = acc;
}

// ---------------- edge scatter: agg[dst] += h[src] * dis[src]*dis[dst] ----------------
// one wave (64 lanes) per edge, lane = channel
__global__ __launch_bounds__(256) void scatter_kernel(
    const int* __restrict__ src, const int* __restrict__ dst,
    const float* __restrict__ dis, const float* __restrict__ h,
    float* __restrict__ agg) {
    int wid = (blockIdx.x * 256 + threadIdx.x) >> 6;
    int lane = threadIdx.x & 63;
    if (wid >= N_EDGES) return;
    int s = src[wid], d = dst[wid];
    float norm = dis[s] * dis[d];
    unsafeAtomicAdd(&agg[d * HID + lane], h[s * HID + lane] * norm);
}

// ---------------- finalize: out = relu(agg + h*dis^2 + b), in place into agg ----------------
__global__ __launch_bounds__(256) void finalize_kernel(
    float* __restrict__ agg, const float* __restrict__ h,
    const float* __restrict__ dis, const float* __restrict__ b) {
    int idx = blockIdx.x * 256 + threadIdx.x;   // grid exactly N_NODES*HID/256
    int v = idx >> 6, j = idx & 63;
    float dv = dis[v];
    float val = agg[idx] + h[idx] * dv * dv + b[j];
    agg[idx] = val > 0.0f ? val : 0.0f;
}

// ---------------- in-place row matmul: x[v] = x[v] @ W2 (64x64) ----------------
__global__ __launch_bounds__(256) void mm2_kernel(float* __restrict__ x,
                                                  const float* __restrict__ W2) {
    __shared__ float W2s[HID * HID];   // 16 KB
    __shared__ float xs[4][HID];
    int t = threadIdx.x;
    for (int i = t; i < HID * HID; i += 256) W2s[i] = W2[i];
    int nl = t >> 6, j = t & 63;
    int v = blockIdx.x * 4 + nl;
    xs[nl][j] = x[v * HID + j];
    __syncthreads();
    float acc = 0.0f;
#pragma unroll
    for (int k = 0; k < HID; ++k) acc = fmaf(xs[nl][k], W2s[k * HID + j], acc);
    x[v * HID + j] = acc;   // safe: row fully staged & synced, each row owned by one block
}

// ---------------- pool: segment-sum over sorted batch ids, run-length flush ----------------
// one wave per 64 consecutive nodes; lane = channel
__global__ __launch_bounds__(256) void pool_kernel(
    const float* __restrict__ x, const int* __restrict__ batch,
    float* __restrict__ sums, int* __restrict__ cnt) {
    int wid = (blockIdx.x * 256 + threadIdx.x) >> 6;
    int lane = threadIdx.x & 63;
    int v0 = wid * 64;
    if (v0 >= N_NODES) return;
    int vend = v0 + 64; if (vend > N_NODES) vend = N_NODES;
    int cur = batch[v0];
    float acc = 0.0f; int run = 0;
    for (int v = v0; v < vend; ++v) {
        int g = batch[v];   // wave-uniform broadcast load
        if (g != cur) {
            unsafeAtomicAdd(&sums[cur * HID + lane], acc);
            if (lane == 0) atomicAdd(&cnt[cur], run);
            acc = 0.0f; run = 0; cur = g;
        }
        acc += x[v * HID + lane];
        run++;
    }
    unsafeAtomicAdd(&sums[cur * HID + lane], acc);
    if (lane == 0) atomicAdd(&cnt[cur], run);
}

// ---------------- logits: out[g] = (sums[g]/max(cnt,1)) @ Wl + bl ----------------
__global__ __launch_bounds__(64) void logits_kernel(
    const float* __restrict__ sums, const int* __restrict__ cnt,
    const float* __restrict__ Wl, const float* __restrict__ bl,
    float* __restrict__ out) {
    __shared__ float row[HID];
    int g = blockIdx.x, t = threadIdx.x;
    int c = cnt[g]; if (c < 1) c = 1;
    row[t] = sums[g * HID + t] / (float)c;
    __syncthreads();
    if (t < N_CLASSES) {
        float acc = bl[t];
#pragma unroll
        for (int k = 0; k < HID; ++k) acc = fmaf(row[k], Wl[k * N_CLASSES + t], acc);
        out[g * N_CLASSES + t] = acc;
    }
}

extern "C" void kernel_launch(void* const* d_in, const int* in_sizes, int n_in,
                              void* d_out, int out_size, void* d_ws, size_t ws_size,
                              hipStream_t stream) {
    const int*   shape_id = (const int*)d_in[0];
    const int*   color_id = (const int*)d_in[1];
    const int*   edge_idx = (const int*)d_in[2];
    const int*   batch    = (const int*)d_in[3];
    const float* st       = (const float*)d_in[4];
    const float* ct       = (const float*)d_in[5];
    const float* W1       = (const float*)d_in[6];
    const float* b1       = (const float*)d_in[7];
    const float* W2       = (const float*)d_in[8];
    const float* b2       = (const float*)d_in[9];
    const float* Wl       = (const float*)d_in[10];
    const float* bl       = (const float*)d_in[11];
    float* out = (float*)d_out;

    const int* src = edge_idx;
    const int* dst = edge_idx + N_EDGES;

    // workspace layout (512B-aligned regions)
    char* ws = (char*)d_ws;
    float* dis    = (float*)(ws + 0);                        // 400000 B
    int*   degi   = (int*)  (ws + 400384);                   // 400000 B
    float* pooled = (float*)(ws + 800768);                   // 262144 B
    int*   cnt    = (int*)  (ws + 1062912);                  // 4096 B
    float* bufA   = (float*)(ws + 1067008);                  // 25.6 MB (h1, later agg2/out2)
    float* bufB   = (float*)(ws + 26667008);                 // 25.6 MB (agg1/out1, later h2)

    const size_t NODE_BUF = (size_t)N_NODES * HID * sizeof(float);

    // zero-init poisoned scratch
    hipMemsetAsync(degi, 0, N_NODES * sizeof(int), stream);
    hipMemsetAsync(pooled, 0, N_GRAPHS * HID * sizeof(float) + N_GRAPHS * sizeof(int) + 0, stream);
    hipMemsetAsync(cnt, 0, N_GRAPHS * sizeof(int), stream);

    // 1. degree + norm
    deg_kernel<<<(N_EDGES + 255) / 256, 256, 0, stream>>>(dst, degi);
    dis_kernel<<<(N_NODES + 255) / 256, 256, 0, stream>>>(degi, dis);

    // 2. h1 = (emb_shape + emb_color) @ W1   -> bufA
    embed_mm1_kernel<<<N_NODES / 4, 256, 0, stream>>>(shape_id, color_id, st, ct, W1, bufA);

    // 3. agg1 scatter -> bufB
    hipMemsetAsync(bufB, 0, NODE_BUF, stream);
    scatter_kernel<<<(N_EDGES * 64) / 256, 256, 0, stream>>>(src, dst, dis, bufA, bufB);

    // 4. out1 = relu(agg1 + h1*dis^2 + b1)  in place in bufB
    finalize_kernel<<<(N_NODES * HID) / 256, 256, 0, stream>>>(bufB, bufA, dis, b1);

    // 5. h2 = out1 @ W2  in place in bufB
    mm2_kernel<<<N_NODES / 4, 256, 0, stream>>>(bufB, W2);

    // 6. agg2 scatter -> bufA
    hipMemsetAsync(bufA, 0, NODE_BUF, stream);
    scatter_kernel<<<(N_EDGES * 64) / 256, 256, 0, stream>>>(src, dst, dis, bufB, bufA);

    // 7. out2 = relu(agg2 + h2*dis^2 + b2)  in place in bufA
    finalize_kernel<<<(N_NODES * HID) / 256, 256, 0, stream>>>(bufA, bufB, dis, b2);

    // 8. pool (sorted batch, run-length flush)
    {
        int waves = (N_NODES + 63) / 64;
        int blocks = (waves * 64 + 255) / 256;
        pool_kernel<<<blocks, 256, 0, stream>>>(bufA, batch, pooled, cnt);
    }

    // 9. logits
    logits_kernel<<<N_GRAPHS, 64, 0, stream>>>(pooled, cnt, Wl, bl, out);
}

// Round 2
// 532.943 us; speedup vs baseline: 1.8758x; 1.8758x over previous
//
#include <hip/hip_runtime.h>
#include <hip/hip_bf16.h>

#define N_NODES   100000
#define N_EDGES   1600000
#define N_GRAPHS  1024
#define EMB       32
#define HID       64
#define N_CLASSES 10
#define SCAN_BLOCKS 391   // ceil(100000/256)

// ---------------- degree count (in-degree over dst) ----------------
__global__ __launch_bounds__(256) void deg_kernel(const int* __restrict__ dst,
                                                  int* __restrict__ degi) {
    int e = blockIdx.x * 256 + threadIdx.x;
    if (e < N_EDGES) atomicAdd(&degi[dst[e]], 1);
}

// ---------------- dis = rsqrt(1+deg); also count nodes per graph ----------------
__global__ __launch_bounds__(256) void dis_cnt_kernel(const int* __restrict__ degi,
                                                      const int* __restrict__ batch,
                                                      float* __restrict__ dis,
                                                      int* __restrict__ cnt) {
    int v = blockIdx.x * 256 + threadIdx.x;
    if (v < N_NODES) {
        dis[v] = rsqrtf(1.0f + (float)degi[v]);
        atomicAdd(&cnt[batch[v]], 1);
    }
}

// ---------------- tiny tables: ST1 = st@W1 (row0=0), CT1 = ct@W1 (row0=0) ----------------
// grid = 26 blocks (17 ST1 rows + 9 CT1 rows), 64 threads = output channel
__global__ __launch_bounds__(64) void tables_kernel(
    const float* __restrict__ st, const float* __restrict__ ct,
    const float* __restrict__ W1, float* __restrict__ ST1, float* __restrict__ CT1) {
    int r = blockIdx.x, j = threadIdx.x;
    if (r < 17) {
        float acc = 0.0f;
        if (r != 0) {
#pragma unroll
            for (int k = 0; k < EMB; ++k) acc = fmaf(st[r * EMB + k], W1[k * HID + j], acc);
        }
        ST1[r * HID + j] = acc;
    } else {
        int rc = r - 17;
        float acc = 0.0f;
        if (rc != 0) {
#pragma unroll
            for (int k = 0; k < EMB; ++k) acc = fmaf(ct[rc * EMB + k], W1[k * HID + j], acc);
        }
        CT1[rc * HID + j] = acc;
    }
}

// ---------------- 3-pass exclusive scan of degi -> rowptr ----------------
__global__ __launch_bounds__(256) void scanA_kernel(const int* __restrict__ degi,
                                                    int* __restrict__ rowptr,
                                                    int* __restrict__ bsum) {
    __shared__ int s[256];
    int t = threadIdx.x, b = blockIdx.x;
    int v = b * 256 + t;
    int d = (v < N_NODES) ? degi[v] : 0;
    s[t] = d; __syncthreads();
#pragma unroll
    for (int off = 1; off < 256; off <<= 1) {
        int x = (t >= off) ? s[t - off] : 0;
        __syncthreads();
        s[t] += x;
        __syncthreads();
    }
    if (v < N_NODES) rowptr[v] = s[t] - d;   // block-local exclusive
    if (t == 255) bsum[b] = s[255];
}

__global__ __launch_bounds__(512) void scanB_kernel(int* __restrict__ bsum) {
    __shared__ int s[512];
    int t = threadIdx.x;
    int d = (t < SCAN_BLOCKS) ? bsum[t] : 0;
    s[t] = d; __syncthreads();
#pragma unroll
    for (int off = 1; off < 512; off <<= 1) {
        int x = (t >= off) ? s[t - off] : 0;
        __syncthreads();
        s[t] += x;
        __syncthreads();
    }
    if (t < SCAN_BLOCKS) bsum[t] = s[t] - d;  // exclusive block offsets
}

__global__ __launch_bounds__(256) void scanC_kernel(int* __restrict__ rowptr,
                                                    int* __restrict__ cursor,
                                                    const int* __restrict__ bsum) {
    int t = threadIdx.x, b = blockIdx.x;
    int v = b * 256 + t;
    if (v < N_NODES) {
        int r = rowptr[v] + bsum[b];
        rowptr[v] = r;
        cursor[v] = r;
    }
    if (b == 0 && t == 0) rowptr[N_NODES] = N_EDGES;
}

// ---------------- CSR fill: bucket edges by dst; store {sid[s],cid[s],dis[s],s} ----------------
__global__ __launch_bounds__(256) void fill_kernel(
    const int* __restrict__ src, const int* __restrict__ dst,
    const int* __restrict__ sid, const int* __restrict__ cid,
    const float* __restrict__ dis, int* __restrict__ cursor,
    int4* __restrict__ eSD) {
    int e = blockIdx.x * 256 + threadIdx.x;
    if (e >= N_EDGES) return;
    int s = src[e], d = dst[e];
    int pos = atomicAdd(&cursor[d], 1);
    int4 q;
    q.x = sid[s];
    q.y = cid[s];
    q.z = __float_as_int(dis[s]);
    q.w = s;
    eSD[pos] = q;
}

// ---------------- layer-1 aggregate (from tables) fused with x1@W2 -> h2 ----------------
// block = 256 = 4 waves; one wave per dst node; lane = channel
__global__ __launch_bounds__(256) void agg1_mm2_kernel(
    const int4* __restrict__ eSD, const int* __restrict__ rowptr,
    const int* __restrict__ sid, const int* __restrict__ cid,
    const float* __restrict__ dis, const float* __restrict__ ST1,
    const float* __restrict__ CT1, const float* __restrict__ W2,
    const float* __restrict__ b1, float* __restrict__ h2) {
    __shared__ float W2s[HID * HID];   // 16 KB
    __shared__ float ST1s[17 * HID];   // 4.25 KB
    __shared__ float CT1s[9 * HID];    // 2.25 KB
    int t = threadIdx.x;
    for (int i = t; i < HID * HID; i += 256) W2s[i] = W2[i];
    for (int i = t; i < 17 * HID; i += 256) ST1s[i] = ST1[i];
    for (int i = t; i < 9 * HID; i += 256) CT1s[i] = CT1[i];
    __syncthreads();

    int v = blockIdx.x * 4 + (t >> 6);   // grid = 25000 exactly, always valid
    int lane = t & 63;
    int e = rowptr[v], end = rowptr[v + 1];
    float acc = 0.0f;
    for (; e + 1 < end; e += 2) {
        int4 q0 = eSD[e], q1 = eSD[e + 1];
        acc = fmaf(ST1s[q0.x * HID + lane] + CT1s[q0.y * HID + lane], __int_as_float(q0.z), acc);
        acc = fmaf(ST1s[q1.x * HID + lane] + CT1s[q1.y * HID + lane], __int_as_float(q1.z), acc);
    }
    if (e < end) {
        int4 q0 = eSD[e];
        acc = fmaf(ST1s[q0.x * HID + lane] + CT1s[q0.y * HID + lane], __int_as_float(q0.z), acc);
    }
    float dv = dis[v];
    float hv = ST1s[sid[v] * HID + lane] + CT1s[cid[v] * HID + lane];
    float val = dv * fmaf(hv, dv, acc) + b1[lane];
    val = val > 0.0f ? val : 0.0f;      // x1[v][lane]

    // h2[v] = x1[v] @ W2  (wave-internal shuffle matmul)
    float acc2 = 0.0f;
#pragma unroll
    for (int k = 0; k < HID; ++k)
        acc2 = fmaf(__shfl(val, k, 64), W2s[k * HID + lane], acc2);
    h2[v * HID + lane] = acc2;
}

// ---------------- layer-2 aggregate + fused mean-pool accumulation ----------------
__global__ __launch_bounds__(256) void agg2_pool_kernel(
    const int4* __restrict__ eSD, const int* __restrict__ rowptr,
    const float* __restrict__ h2, const float* __restrict__ dis,
    const float* __restrict__ b2, const int* __restrict__ batch,
    float* __restrict__ pooled) {
    int t = threadIdx.x;
    int v = blockIdx.x * 4 + (t >> 6);
    int lane = t & 63;
    int e = rowptr[v], end = rowptr[v + 1];
    float acc = 0.0f;
    for (; e + 1 < end; e += 2) {
        int4 q0 = eSD[e], q1 = eSD[e + 1];
        float g0 = h2[(size_t)q0.w * HID + lane];
        float g1 = h2[(size_t)q1.w * HID + lane];
        acc = fmaf(g0, __int_as_float(q0.z), acc);
        acc = fmaf(g1, __int_as_float(q1.z), acc);
    }
    if (e < end) {
        int4 q0 = eSD[e];
        acc = fmaf(h2[(size_t)q0.w * HID + lane], __int_as_float(q0.z), acc);
    }
    float dv = dis[v];
    float val = dv * fmaf(h2[v * HID + lane], dv, acc) + b2[lane];
    val = val > 0.0f ? val : 0.0f;      // x2[v][lane]
    int g = batch[v];
    unsafeAtomicAdd(&pooled[g * HID + lane], val);
}

// ---------------- logits: out[g] = (pooled[g]/max(cnt,1)) @ Wl + bl ----------------
__global__ __launch_bounds__(64) void logits_kernel(
    const float* __restrict__ pooled, const int* __restrict__ cnt,
    const float* __restrict__ Wl, const float* __restrict__ bl,
    float* __restrict__ out) {
    __shared__ float row[HID];
    int g = blockIdx.x, t = threadIdx.x;
    int c = cnt[g]; if (c < 1) c = 1;
    row[t] = pooled[g * HID + t] / (float)c;
    __syncthreads();
    if (t < N_CLASSES) {
        float acc = bl[t];
#pragma unroll
        for (int k = 0; k < HID; ++k) acc = fmaf(row[k], Wl[k * N_CLASSES + t], acc);
        out[g * N_CLASSES + t] = acc;
    }
}

extern "C" void kernel_launch(void* const* d_in, const int* in_sizes, int n_in,
                              void* d_out, int out_size, void* d_ws, size_t ws_size,
                              hipStream_t stream) {
    const int*   shape_id = (const int*)d_in[0];
    const int*   color_id = (const int*)d_in[1];
    const int*   edge_idx = (const int*)d_in[2];
    const int*   batch    = (const int*)d_in[3];
    const float* st       = (const float*)d_in[4];
    const float* ct       = (const float*)d_in[5];
    const float* W1       = (const float*)d_in[6];
    const float* b1       = (const float*)d_in[7];
    const float* W2       = (const float*)d_in[8];
    const float* b2       = (const float*)d_in[9];
    const float* Wl       = (const float*)d_in[10];
    const float* bl       = (const float*)d_in[11];
    float* out = (float*)d_out;

    const int* src = edge_idx;
    const int* dst = edge_idx + N_EDGES;

    // workspace layout (512B-aligned)
    char* ws = (char*)d_ws;
    float* dis    = (float*)(ws + 0);            // 400,000 B
    int*   degi   = (int*)  (ws + 400384);       // 400,000 B
    int*   rowptr = (int*)  (ws + 800768);       // 400,004 B
    int*   cursor = (int*)  (ws + 1201664);      // 400,000 B
    int*   bsum   = (int*)  (ws + 1602048);      // 2,048 B
    float* ST1    = (float*)(ws + 1604096);      // 4,352 B
    float* CT1    = (float*)(ws + 1608960);      // 2,304 B
    float* pooled = (float*)(ws + 1611776);      // 262,144 B
    int*   cnt    = (int*)  (ws + 1873920);      // 4,096 B
    int4*  eSD    = (int4*) (ws + 1878016);      // 25,600,000 B
    float* h2     = (float*)(ws + 27478016);     // 25,600,000 B  (total ~53.1 MB)

    // zero poisoned scratch
    hipMemsetAsync(degi, 0, N_NODES * sizeof(int), stream);
    hipMemsetAsync(pooled, 0, N_GRAPHS * HID * sizeof(float), stream);
    hipMemsetAsync(cnt, 0, N_GRAPHS * sizeof(int), stream);

    // 1. degree, norms, per-graph counts
    deg_kernel<<<(N_EDGES + 255) / 256, 256, 0, stream>>>(dst, degi);
    dis_cnt_kernel<<<SCAN_BLOCKS, 256, 0, stream>>>(degi, batch, dis, cnt);

    // 2. embedding x W1 tables
    tables_kernel<<<26, 64, 0, stream>>>(st, ct, W1, ST1, CT1);

    // 3. exclusive scan -> rowptr, cursor
    scanA_kernel<<<SCAN_BLOCKS, 256, 0, stream>>>(degi, rowptr, bsum);
    scanB_kernel<<<1, 512, 0, stream>>>(bsum);
    scanC_kernel<<<SCAN_BLOCKS, 256, 0, stream>>>(rowptr, cursor, bsum);

    // 4. CSR fill with per-edge {sid,cid,dis,src}
    fill_kernel<<<(N_EDGES + 255) / 256, 256, 0, stream>>>(src, dst, shape_id, color_id,
                                                           dis, cursor, eSD);

    // 5. layer-1 aggregate (table-based) + fused @W2 -> h2
    agg1_mm2_kernel<<<N_NODES / 4, 256, 0, stream>>>(eSD, rowptr, shape_id, color_id,
                                                     dis, ST1, CT1, W2, b1, h2);

    // 6. layer-2 aggregate + fused pool accumulation
    agg2_pool_kernel<<<N_NODES / 4, 256, 0, stream>>>(eSD, rowptr, h2, dis, b2, batch, pooled);

    // 7. logits
    logits_kernel<<<N_GRAPHS, 64, 0, stream>>>(pooled, cnt, Wl, bl, out);
}

// Round 3
// 497.088 us; speedup vs baseline: 2.0111x; 1.0721x over previous
//
#include <hip/hip_runtime.h>
#include <hip/hip_bf16.h>

#define N_NODES   100000
#define N_EDGES   1600000
#define N_GRAPHS  1024
#define EMB       32
#define HID       64
#define N_CLASSES 10
#define SCAN_BLOCKS 391   // ceil(100000/256)
#define NPW 16            // nodes per wave in agg1 (amortizes W2-column register load)

// ---------------- degree count (in-degree over dst) ----------------
__global__ __launch_bounds__(256) void deg_kernel(const int* __restrict__ dst,
                                                  int* __restrict__ degi) {
    int e = blockIdx.x * 256 + threadIdx.x;
    if (e < N_EDGES) atomicAdd(&degi[dst[e]], 1);
}

// ---------------- dis = rsqrt(1+deg); also count nodes per graph ----------------
__global__ __launch_bounds__(256) void dis_cnt_kernel(const int* __restrict__ degi,
                                                      const int* __restrict__ batch,
                                                      float* __restrict__ dis,
                                                      int* __restrict__ cnt) {
    int v = blockIdx.x * 256 + threadIdx.x;
    if (v < N_NODES) {
        dis[v] = rsqrtf(1.0f + (float)degi[v]);
        atomicAdd(&cnt[batch[v]], 1);
    }
}

// ---------------- tiny tables: ST1 = st@W1 (row0=0), CT1 = ct@W1 (row0=0) ----------------
__global__ __launch_bounds__(64) void tables_kernel(
    const float* __restrict__ st, const float* __restrict__ ct,
    const float* __restrict__ W1, float* __restrict__ ST1, float* __restrict__ CT1) {
    int r = blockIdx.x, j = threadIdx.x;
    if (r < 17) {
        float acc = 0.0f;
        if (r != 0) {
#pragma unroll
            for (int k = 0; k < EMB; ++k) acc = fmaf(st[r * EMB + k], W1[k * HID + j], acc);
        }
        ST1[r * HID + j] = acc;
    } else {
        int rc = r - 17;
        float acc = 0.0f;
        if (rc != 0) {
#pragma unroll
            for (int k = 0; k < EMB; ++k) acc = fmaf(ct[rc * EMB + k], W1[k * HID + j], acc);
        }
        CT1[rc * HID + j] = acc;
    }
}

// ---------------- 3-pass exclusive scan of degi -> rowptr ----------------
__global__ __launch_bounds__(256) void scanA_kernel(const int* __restrict__ degi,
                                                    int* __restrict__ rowptr,
                                                    int* __restrict__ bsum) {
    __shared__ int s[256];
    int t = threadIdx.x, b = blockIdx.x;
    int v = b * 256 + t;
    int d = (v < N_NODES) ? degi[v] : 0;
    s[t] = d; __syncthreads();
#pragma unroll
    for (int off = 1; off < 256; off <<= 1) {
        int x = (t >= off) ? s[t - off] : 0;
        __syncthreads();
        s[t] += x;
        __syncthreads();
    }
    if (v < N_NODES) rowptr[v] = s[t] - d;
    if (t == 255) bsum[b] = s[255];
}

__global__ __launch_bounds__(512) void scanB_kernel(int* __restrict__ bsum) {
    __shared__ int s[512];
    int t = threadIdx.x;
    int d = (t < SCAN_BLOCKS) ? bsum[t] : 0;
    s[t] = d; __syncthreads();
#pragma unroll
    for (int off = 1; off < 512; off <<= 1) {
        int x = (t >= off) ? s[t - off] : 0;
        __syncthreads();
        s[t] += x;
        __syncthreads();
    }
    if (t < SCAN_BLOCKS) bsum[t] = s[t] - d;
}

__global__ __launch_bounds__(256) void scanC_kernel(int* __restrict__ rowptr,
                                                    int* __restrict__ cursor,
                                                    const int* __restrict__ bsum) {
    int t = threadIdx.x, b = blockIdx.x;
    int v = b * 256 + t;
    if (v < N_NODES) {
        int r = rowptr[v] + bsum[b];
        rowptr[v] = r;
        cursor[v] = r;
    }
    if (b == 0 && t == 0) rowptr[N_NODES] = N_EDGES;
}

// ---------------- CSR fill: 8B records {src | sid<<17 | cid<<22, dis} ----------------
__global__ __launch_bounds__(256) void fill_kernel(
    const int* __restrict__ src, const int* __restrict__ dst,
    const int* __restrict__ sid, const int* __restrict__ cid,
    const float* __restrict__ dis, int* __restrict__ cursor,
    int2* __restrict__ epack) {
    int e = blockIdx.x * 256 + threadIdx.x;
    if (e >= N_EDGES) return;
    int s = src[e], d = dst[e];
    int pos = atomicAdd(&cursor[d], 1);
    int2 q;
    q.x = s | (sid[s] << 17) | (cid[s] << 22);   // src<2^17, sid<32, cid<16
    q.y = __float_as_int(dis[s]);
    epack[pos] = q;
}

// ---------------- layer-1 aggregate + fused x1@W2 -> h2 ----------------
// block = 4 waves; each wave handles NPW consecutive nodes; lane = channel.
// W2 column held in 64 VGPRs per thread (loaded coalesced from global once/wave).
__global__ __launch_bounds__(256) void agg1_mm2_kernel(
    const int2* __restrict__ epack, const int* __restrict__ rowptr,
    const int* __restrict__ sid, const int* __restrict__ cid,
    const float* __restrict__ dis, const float* __restrict__ ST1,
    const float* __restrict__ CT1, const float* __restrict__ W2,
    const float* __restrict__ b1, float* __restrict__ h2) {
    __shared__ float ST1s[17 * HID];              // 4.25 KB
    __shared__ float CT1s[9 * HID];               // 2.25 KB
    __shared__ __align__(16) float xs[4][HID];    // 1 KB (per-wave x1 staging)
    int t = threadIdx.x;
    for (int i = t; i < 17 * HID; i += 256) ST1s[i] = ST1[i];
    for (int i = t; i < 9 * HID; i += 256) CT1s[i] = CT1[i];
    __syncthreads();

    int lane = t & 63, w = t >> 6;
    // W2 column -> registers (coalesced: fixed k, lanes read consecutive floats)
    float wcol[HID];
#pragma unroll
    for (int k = 0; k < HID; ++k) wcol[k] = W2[k * HID + lane];
    float bias = b1[lane];

    int v0 = (blockIdx.x * 4 + w) * NPW;
    for (int n = 0; n < NPW; ++n) {
        int v = v0 + n;
        if (v >= N_NODES) return;
        int e = rowptr[v], end = rowptr[v + 1];
        float acc = 0.0f;
        for (; e + 1 < end; e += 2) {
            int2 q0 = epack[e], q1 = epack[e + 1];
            int s0 = (q0.x >> 17) & 31, c0 = (unsigned)q0.x >> 22;
            int s1 = (q1.x >> 17) & 31, c1 = (unsigned)q1.x >> 22;
            acc = fmaf(ST1s[s0 * HID + lane] + CT1s[c0 * HID + lane], __int_as_float(q0.y), acc);
            acc = fmaf(ST1s[s1 * HID + lane] + CT1s[c1 * HID + lane], __int_as_float(q1.y), acc);
        }
        if (e < end) {
            int2 q0 = epack[e];
            int s0 = (q0.x >> 17) & 31, c0 = (unsigned)q0.x >> 22;
            acc = fmaf(ST1s[s0 * HID + lane] + CT1s[c0 * HID + lane], __int_as_float(q0.y), acc);
        }
        float dv = dis[v];
        float hv = ST1s[sid[v] * HID + lane] + CT1s[cid[v] * HID + lane];
        float val = dv * fmaf(hv, dv, acc) + bias;
        val = val > 0.0f ? val : 0.0f;            // x1[v][lane]

        // h2[v][lane] = sum_k x1[v][k] * W2[k][lane] via LDS broadcast + register W2
        xs[w][lane] = val;                         // wave-coherent; lgkmcnt ordering only
        float acc2 = 0.0f;
#pragma unroll
        for (int k4 = 0; k4 < HID / 4; ++k4) {
            float4 xv = *reinterpret_cast<const float4*>(&xs[w][k4 * 4]);  // broadcast read
            acc2 = fmaf(xv.x, wcol[k4 * 4 + 0], acc2);
            acc2 = fmaf(xv.y, wcol[k4 * 4 + 1], acc2);
            acc2 = fmaf(xv.z, wcol[k4 * 4 + 2], acc2);
            acc2 = fmaf(xv.w, wcol[k4 * 4 + 3], acc2);
        }
        h2[(size_t)v * HID + lane] = acc2;
    }
}

// ---------------- layer-2 aggregate + fused mean-pool accumulation ----------------
__global__ __launch_bounds__(256) void agg2_pool_kernel(
    const int2* __restrict__ epack, const int* __restrict__ rowptr,
    const float* __restrict__ h2, const float* __restrict__ dis,
    const float* __restrict__ b2, const int* __restrict__ batch,
    float* __restrict__ pooled) {
    int t = threadIdx.x;
    int v = blockIdx.x * 4 + (t >> 6);
    int lane = t & 63;
    int e = rowptr[v], end = rowptr[v + 1];
    float acc = 0.0f;
    for (; e + 1 < end; e += 2) {
        int2 q0 = epack[e], q1 = epack[e + 1];
        int s0 = q0.x & 0x1FFFF, s1 = q1.x & 0x1FFFF;
        float g0 = h2[(size_t)s0 * HID + lane];
        float g1 = h2[(size_t)s1 * HID + lane];
        acc = fmaf(g0, __int_as_float(q0.y), acc);
        acc = fmaf(g1, __int_as_float(q1.y), acc);
    }
    if (e < end) {
        int2 q0 = epack[e];
        int s0 = q0.x & 0x1FFFF;
        acc = fmaf(h2[(size_t)s0 * HID + lane], __int_as_float(q0.y), acc);
    }
    float dv = dis[v];
    float val = dv * fmaf(h2[(size_t)v * HID + lane], dv, acc) + b2[lane];
    val = val > 0.0f ? val : 0.0f;
    unsafeAtomicAdd(&pooled[batch[v] * HID + lane], val);
}

// ---------------- logits ----------------
__global__ __launch_bounds__(64) void logits_kernel(
    const float* __restrict__ pooled, const int* __restrict__ cnt,
    const float* __restrict__ Wl, const float* __restrict__ bl,
    float* __restrict__ out) {
    __shared__ float row[HID];
    int g = blockIdx.x, t = threadIdx.x;
    int c = cnt[g]; if (c < 1) c = 1;
    row[t] = pooled[g * HID + t] / (float)c;
    __syncthreads();
    if (t < N_CLASSES) {
        float acc = bl[t];
#pragma unroll
        for (int k = 0; k < HID; ++k) acc = fmaf(row[k], Wl[k * N_CLASSES + t], acc);
        out[g * N_CLASSES + t] = acc;
    }
}

extern "C" void kernel_launch(void* const* d_in, const int* in_sizes, int n_in,
                              void* d_out, int out_size, void* d_ws, size_t ws_size,
                              hipStream_t stream) {
    const int*   shape_id = (const int*)d_in[0];
    const int*   color_id = (const int*)d_in[1];
    const int*   edge_idx = (const int*)d_in[2];
    const int*   batch    = (const int*)d_in[3];
    const float* st       = (const float*)d_in[4];
    const float* ct       = (const float*)d_in[5];
    const float* W1       = (const float*)d_in[6];
    const float* b1       = (const float*)d_in[7];
    const float* W2       = (const float*)d_in[8];
    const float* b2       = (const float*)d_in[9];
    const float* Wl       = (const float*)d_in[10];
    const float* bl       = (const float*)d_in[11];
    float* out = (float*)d_out;

    const int* src = edge_idx;
    const int* dst = edge_idx + N_EDGES;

    // workspace layout (512B-aligned)
    char* ws = (char*)d_ws;
    float* dis    = (float*)(ws + 0);            // 400,000 B
    int*   degi   = (int*)  (ws + 400384);
    int*   rowptr = (int*)  (ws + 800768);       // 400,004 B
    int*   cursor = (int*)  (ws + 1201664);
    int*   bsum   = (int*)  (ws + 1602048);      // 2,048 B
    float* ST1    = (float*)(ws + 1604096);      // 4,352 B
    float* CT1    = (float*)(ws + 1608960);      // 2,304 B
    float* pooled = (float*)(ws + 1611776);      // 262,144 B
    int*   cnt    = (int*)  (ws + 1873920);      // 4,096 B
    int2*  epack  = (int2*) (ws + 1878016);      // 12,800,000 B
    float* h2     = (float*)(ws + 14678016);     // 25,600,000 B  (total ~40.3 MB)

    hipMemsetAsync(degi, 0, N_NODES * sizeof(int), stream);
    hipMemsetAsync(pooled, 0, N_GRAPHS * HID * sizeof(float), stream);
    hipMemsetAsync(cnt, 0, N_GRAPHS * sizeof(int), stream);

    // 1. degree, norms, per-graph counts
    deg_kernel<<<(N_EDGES + 255) / 256, 256, 0, stream>>>(dst, degi);
    dis_cnt_kernel<<<SCAN_BLOCKS, 256, 0, stream>>>(degi, batch, dis, cnt);

    // 2. embedding x W1 tables
    tables_kernel<<<26, 64, 0, stream>>>(st, ct, W1, ST1, CT1);

    // 3. exclusive scan -> rowptr, cursor
    scanA_kernel<<<SCAN_BLOCKS, 256, 0, stream>>>(degi, rowptr, bsum);
    scanB_kernel<<<1, 512, 0, stream>>>(bsum);
    scanC_kernel<<<SCAN_BLOCKS, 256, 0, stream>>>(rowptr, cursor, bsum);

    // 4. CSR fill (8B records)
    fill_kernel<<<(N_EDGES + 255) / 256, 256, 0, stream>>>(src, dst, shape_id, color_id,
                                                           dis, cursor, epack);

    // 5. layer-1 aggregate + fused @W2 -> h2
    {
        int waves = (N_NODES + NPW - 1) / NPW;          // 6250
        int blocks = (waves + 3) / 4;                    // 1563
        agg1_mm2_kernel<<<blocks, 256, 0, stream>>>(epack, rowptr, shape_id, color_id,
                                                    dis, ST1, CT1, W2, b1, h2);
    }

    // 6. layer-2 aggregate + fused pool accumulation
    agg2_pool_kernel<<<N_NODES / 4, 256, 0, stream>>>(epack, rowptr, h2, dis, b2, batch, pooled);

    // 7. logits
    logits_kernel<<<N_GRAPHS, 64, 0, stream>>>(pooled, cnt, Wl, bl, out);
}

// Round 4
// 447.713 us; speedup vs baseline: 2.2329x; 1.1103x over previous
//
#include <hip/hip_runtime.h>
#include <hip/hip_bf16.h>

#define N_NODES   100000
#define N_EDGES   1600000
#define N_GRAPHS  1024
#define EMB       32
#define HID       64
#define N_CLASSES 10
#define SCAN_BLOCKS 391   // ceil(100000/256)
#define NCOMBO 153        // 17 shape ids x 9 color ids

// ---------------- degree count (in-degree over dst) ----------------
__global__ __launch_bounds__(256) void deg_kernel(const int* __restrict__ dst,
                                                  int* __restrict__ degi) {
    int e = blockIdx.x * 256 + threadIdx.x;
    if (e < N_EDGES) atomicAdd(&degi[dst[e]], 1);
}

// ---------------- prep: pk[v] = {v | combo<<17, dis}; per-graph counts ----------------
__global__ __launch_bounds__(256) void prep_kernel(
    const int* __restrict__ degi, const int* __restrict__ sid,
    const int* __restrict__ cid, const int* __restrict__ batch,
    int2* __restrict__ pk, int* __restrict__ cnt) {
    int v = blockIdx.x * 256 + threadIdx.x;
    if (v < N_NODES) {
        float dv = rsqrtf(1.0f + (float)degi[v]);
        int combo = sid[v] * 9 + cid[v];          // 0..152
        int2 p; p.x = v | (combo << 17); p.y = __float_as_int(dv);
        pk[v] = p;
        atomicAdd(&cnt[batch[v]], 1);
    }
}

// ---------------- combined table: TC[s*9+c][j] = (st[s]@W1)[j] + (ct[c]@W1)[j], rows 0 zero ----------------
__global__ __launch_bounds__(64) void tc_kernel(
    const float* __restrict__ st, const float* __restrict__ ct,
    const float* __restrict__ W1, float* __restrict__ TC) {
    int r = blockIdx.x, j = threadIdx.x;
    int s = r / 9, c = r % 9;
    float acc = 0.0f;
    if (s != 0) {
#pragma unroll
        for (int k = 0; k < EMB; ++k) acc = fmaf(st[s * EMB + k], W1[k * HID + j], acc);
    }
    if (c != 0) {
#pragma unroll
        for (int k = 0; k < EMB; ++k) acc = fmaf(ct[c * EMB + k], W1[k * HID + j], acc);
    }
    TC[r * HID + j] = acc;
}

// ---------------- 3-pass exclusive scan over PADDED degrees ((d+7)&~7) -> rowptr ----------------
__global__ __launch_bounds__(256) void scanA_kernel(const int* __restrict__ degi,
                                                    int* __restrict__ rowptr,
                                                    int* __restrict__ bsum) {
    __shared__ int s[256];
    int t = threadIdx.x, b = blockIdx.x;
    int v = b * 256 + t;
    int d = (v < N_NODES) ? ((degi[v] + 7) & ~7) : 0;
    s[t] = d; __syncthreads();
#pragma unroll
    for (int off = 1; off < 256; off <<= 1) {
        int x = (t >= off) ? s[t - off] : 0;
        __syncthreads();
        s[t] += x;
        __syncthreads();
    }
    if (v < N_NODES) rowptr[v] = s[t] - d;
    if (t == 255) bsum[b] = s[255];
}

__global__ __launch_bounds__(512) void scanB_kernel(int* __restrict__ bsum) {
    __shared__ int s[512];
    int t = threadIdx.x;
    int d = (t < SCAN_BLOCKS) ? bsum[t] : 0;
    s[t] = d; __syncthreads();
#pragma unroll
    for (int off = 1; off < 512; off <<= 1) {
        int x = (t >= off) ? s[t - off] : 0;
        __syncthreads();
        s[t] += x;
        __syncthreads();
    }
    if (t < SCAN_BLOCKS) bsum[t] = s[t] - d;
}

__global__ __launch_bounds__(256) void scanC_kernel(int* __restrict__ rowptr,
                                                    int* __restrict__ cursor,
                                                    const int* __restrict__ bsum,
                                                    const int* __restrict__ degi) {
    int t = threadIdx.x, b = blockIdx.x;
    int v = b * 256 + t;
    if (v < N_NODES) {
        int r = rowptr[v] + bsum[b];
        rowptr[v] = r;
        cursor[v] = r;
        if (v == N_NODES - 1) rowptr[N_NODES] = r + ((degi[v] + 7) & ~7);
    }
}

// ---------------- CSR fill: epack[pos] = pk[src] (pad slots stay {0,0} from memset) ----------------
__global__ __launch_bounds__(256) void fill_kernel(
    const int* __restrict__ src, const int* __restrict__ dst,
    const int2* __restrict__ pk, int* __restrict__ cursor,
    int2* __restrict__ epack) {
    int e = blockIdx.x * 256 + threadIdx.x;
    if (e >= N_EDGES) return;
    int s = src[e], d = dst[e];
    int2 p = pk[s];
    int pos = atomicAdd(&cursor[d], 1);
    epack[pos] = p;
}

// ---------------- layer-1 aggregate from combined table -> x1 ----------------
// 4 waves/block, 4 nodes/wave (grid 6250); lane = channel; edge bounds scalarized.
__global__ __launch_bounds__(256) void agg1_kernel(
    const int2* __restrict__ epack, const int* __restrict__ rowptr,
    const int2* __restrict__ pk, const float* __restrict__ TC,
    const float* __restrict__ b1, float* __restrict__ x1) {
    __shared__ __align__(16) float TCs[NCOMBO * HID];   // 39,168 B
    int t = threadIdx.x;
    {
        const float4* s4 = (const float4*)TC;
        float4* d4 = (float4*)TCs;
        for (int i = t; i < NCOMBO * HID / 4; i += 256) d4[i] = s4[i];
    }
    __syncthreads();
    int lane = t & 63, w = t >> 6;
    float bias = b1[lane];
    int v0 = (blockIdx.x * 4 + w) * 4;
    for (int n = 0; n < 4; ++n) {
        int v = v0 + n;
        int e  = __builtin_amdgcn_readfirstlane(rowptr[v]);
        int e1 = __builtin_amdgcn_readfirstlane(rowptr[v + 1]);
        float acc = 0.0f;
        for (; e < e1; e += 8) {          // padded: exact multiple of 8
#pragma unroll
            for (int i = 0; i < 8; ++i) {
                int2 q = epack[e + i];    // uniform address -> s_load
                acc = fmaf(__int_as_float(q.y),
                           TCs[((unsigned)q.x >> 17) * HID + lane], acc);
            }
        }
        int2 pv = pk[v];
        float dv = __int_as_float(pv.y);
        float hv = TCs[((unsigned)pv.x >> 17) * HID + lane];
        float val = dv * fmaf(hv, dv, acc) + bias;
        x1[(size_t)v * HID + lane] = val > 0.0f ? val : 0.0f;
    }
}

// ---------------- mm2 in place: x[v] = x[v] @ W2; W2 column held in 64 VGPRs ----------------
__global__ __launch_bounds__(256, 1) void mm2_kernel(float* __restrict__ x,
                                                     const float* __restrict__ W2) {
    __shared__ __align__(16) float xs[4][HID];
    int t = threadIdx.x, lane = t & 63, w = t >> 6;
    float wcol[HID];
#pragma unroll
    for (int k = 0; k < HID; ++k) wcol[k] = W2[k * HID + lane];
    int v0 = (blockIdx.x * 4 + w) * 16;
    for (int n = 0; n < 16; ++n) {
        int v = v0 + n;
        if (v >= N_NODES) return;
        xs[w][lane] = x[(size_t)v * HID + lane];   // wave-private row staging
        float acc = 0.0f;
#pragma unroll
        for (int k4 = 0; k4 < HID / 4; ++k4) {
            float4 xv = *(const float4*)(&xs[w][k4 * 4]);   // broadcast read
            acc = fmaf(xv.x, wcol[k4 * 4 + 0], acc);
            acc = fmaf(xv.y, wcol[k4 * 4 + 1], acc);
            acc = fmaf(xv.z, wcol[k4 * 4 + 2], acc);
            acc = fmaf(xv.w, wcol[k4 * 4 + 3], acc);
        }
        x[(size_t)v * HID + lane] = acc;           // row fully staged; safe in place
    }
}

// ---------------- layer-2 aggregate + fused mean-pool accumulation ----------------
__global__ __launch_bounds__(256) void agg2_pool_kernel(
    const int2* __restrict__ epack, const int* __restrict__ rowptr,
    const float* __restrict__ h2, const int2* __restrict__ pk,
    const float* __restrict__ b2, const int* __restrict__ batch,
    float* __restrict__ pooled) {
    int t = threadIdx.x, lane = t & 63;
    int v = blockIdx.x * 4 + (t >> 6);
    int e  = __builtin_amdgcn_readfirstlane(rowptr[v]);
    int e1 = __builtin_amdgcn_readfirstlane(rowptr[v + 1]);
    float acc = 0.0f;
    for (; e < e1; e += 8) {
#pragma unroll
        for (int i = 0; i < 8; ++i) {
            int2 q = epack[e + i];
            int s = q.x & 0x1FFFF;
            acc = fmaf(__int_as_float(q.y), h2[(size_t)s * HID + lane], acc);
        }
    }
    int2 pv = pk[v];
    float dv = __int_as_float(pv.y);
    float val = dv * fmaf(h2[(size_t)v * HID + lane], dv, acc) + b2[lane];
    val = val > 0.0f ? val : 0.0f;
    unsafeAtomicAdd(&pooled[batch[v] * HID + lane], val);
}

// ---------------- logits ----------------
__global__ __launch_bounds__(64) void logits_kernel(
    const float* __restrict__ pooled, const int* __restrict__ cnt,
    const float* __restrict__ Wl, const float* __restrict__ bl,
    float* __restrict__ out) {
    __shared__ float row[HID];
    int g = blockIdx.x, t = threadIdx.x;
    int c = cnt[g]; if (c < 1) c = 1;
    row[t] = pooled[g * HID + t] / (float)c;
    __syncthreads();
    if (t < N_CLASSES) {
        float acc = bl[t];
#pragma unroll
        for (int k = 0; k < HID; ++k) acc = fmaf(row[k], Wl[k * N_CLASSES + t], acc);
        out[g * N_CLASSES + t] = acc;
    }
}

extern "C" void kernel_launch(void* const* d_in, const int* in_sizes, int n_in,
                              void* d_out, int out_size, void* d_ws, size_t ws_size,
                              hipStream_t stream) {
    const int*   shape_id = (const int*)d_in[0];
    const int*   color_id = (const int*)d_in[1];
    const int*   edge_idx = (const int*)d_in[2];
    const int*   batch    = (const int*)d_in[3];
    const float* st       = (const float*)d_in[4];
    const float* ct       = (const float*)d_in[5];
    const float* W1       = (const float*)d_in[6];
    const float* b1       = (const float*)d_in[7];
    const float* W2       = (const float*)d_in[8];
    const float* b2       = (const float*)d_in[9];
    const float* Wl       = (const float*)d_in[10];
    const float* bl       = (const float*)d_in[11];
    float* out = (float*)d_out;

    const int* src = edge_idx;
    const int* dst = edge_idx + N_EDGES;

    // workspace layout
    char* ws = (char*)d_ws;
    int2*  pk     = (int2*) (ws + 0);            //   800,000 B
    int*   degi   = (int*)  (ws + 800256);       //   400,000 B
    int*   rowptr = (int*)  (ws + 1200256);      //   400,004 B
    int*   cursor = (int*)  (ws + 1600512);      //   400,000 B
    int*   bsum   = (int*)  (ws + 2000512);      //     2,048 B
    float* TC     = (float*)(ws + 2002560);      //    39,168 B
    float* pooled = (float*)(ws + 2041728);      //   262,144 B
    int*   cnt    = (int*)  (ws + 2303872);      //     4,096 B
    int2*  epack  = (int2*) (ws + 2307968);      // 18,400,000 B (padded CSR, max 2.3M recs)
    float* x1h2   = (float*)(ws + 20707968);     // 25,600,000 B  (total ~46.3 MB)

    hipMemsetAsync(degi, 0, N_NODES * sizeof(int), stream);
    hipMemsetAsync(pooled, 0, N_GRAPHS * HID * sizeof(float) + N_GRAPHS * sizeof(int), stream);
    hipMemsetAsync(epack, 0, 18400000, stream);  // pad records must be {src=0,combo=0,w=0}

    // 1. degrees
    deg_kernel<<<(N_EDGES + 255) / 256, 256, 0, stream>>>(dst, degi);

    // 2. per-node packed key {v|combo<<17, dis} + per-graph counts
    prep_kernel<<<SCAN_BLOCKS, 256, 0, stream>>>(degi, shape_id, color_id, batch, pk, cnt);

    // 3. combined (shape,color)->h1 table
    tc_kernel<<<NCOMBO, 64, 0, stream>>>(st, ct, W1, TC);

    // 4. exclusive scan over padded degrees
    scanA_kernel<<<SCAN_BLOCKS, 256, 0, stream>>>(degi, rowptr, bsum);
    scanB_kernel<<<1, 512, 0, stream>>>(bsum);
    scanC_kernel<<<SCAN_BLOCKS, 256, 0, stream>>>(rowptr, cursor, bsum, degi);

    // 5. CSR fill
    fill_kernel<<<(N_EDGES + 255) / 256, 256, 0, stream>>>(src, dst, pk, cursor, epack);

    // 6. layer-1 aggregate -> x1
    agg1_kernel<<<6250, 256, 0, stream>>>(epack, rowptr, pk, TC, b1, x1h2);

    // 7. x1 @ W2 in place -> h2
    mm2_kernel<<<1563, 256, 0, stream>>>(x1h2, W2);

    // 8. layer-2 aggregate + pool
    agg2_pool_kernel<<<N_NODES / 4, 256, 0, stream>>>(epack, rowptr, x1h2, pk, b2, batch, pooled);

    // 9. logits
    logits_kernel<<<N_GRAPHS, 64, 0, stream>>>(pooled, cnt, Wl, bl, out);
}